// Round 9
// baseline (170.138 us; speedup 1.0000x reference)
//
#include <hip/hip_runtime.h>
#include <math.h>

// DifferentiableKalmanCell: B=4096, STATE=64, OBS=32, coeffs (64,64,11), t scalar.
// One block per batch; MFMA (bf16 split hi/lo) for all GEMM phases; S^-1 by
// single-wave register Gauss-Jordan.
// R9: 512-thread blocks (8 waves). LDS stays 40960 => 4 blocks/CU => 32 waves/CU
// (hardware max, 2x r8) for latency hiding. Each GEMM phase splits across wave
// pairs: wave w -> row band (w>>1), column half (w&1). Band-locality is gone,
// so T/cov writes get their own barriers (10 total).
// LDS 40960:
//   @0     R1: P-split(u16 [64][64] swz x2) -> T(u32 packed) -> PHt | K
//   @16384 R2: F-split -> cov(u32 packed)
//   @32768 EX: p0-p1: chT[64][12] | dcT[64][12] | ypart[8][64]
//              post-B1: sy | sresid | sq | sr | sS[32][36]

typedef float f4 __attribute__((ext_vector_type(4)));
typedef float f32x4 __attribute__((ext_vector_type(4)));
typedef short b16x8 __attribute__((ext_vector_type(8)));
typedef short b16x4 __attribute__((ext_vector_type(4)));
typedef unsigned int u32;
typedef unsigned int u32x4 __attribute__((ext_vector_type(4)));
typedef unsigned short u16;

#define EPSC 1e-7f
#define MFMA(a, b, c) __builtin_amdgcn_mfma_f32_16x16x32_bf16(a, b, c, 0, 0, 0)
static constexpr size_t CU_OFF = 4096 * 64;
static constexpr size_t CD_OFF = CU_OFF + 4096ull * 4096;

__device__ __forceinline__ void split2(float x, short &h, short &l) {
  u32 u = __float_as_uint(x);
  h = (short)(u >> 16);
  float rem = x - __uint_as_float(u & 0xffff0000u);
  l = (short)(__float_as_uint(rem) >> 16);
}
__device__ __forceinline__ u32 packsplit(float x) {
  u32 u = __float_as_uint(x) & 0xffff0000u;
  float rem = x - __uint_as_float(u);
  return u | (__float_as_uint(rem) >> 16);
}
__device__ __forceinline__ float unpackf(u32 v) {
  return __uint_as_float(v & 0xffff0000u) + __uint_as_float(v << 16);
}
union U8 { u32x4 u; b16x8 s; };
__device__ __forceinline__ void unpack8(u32x4 q0, u32x4 q1, b16x8 &hi,
                                        b16x8 &lo) {
  U8 H, L;
  H.u[0] = __builtin_amdgcn_perm(q0[1], q0[0], 0x07060302u);
  H.u[1] = __builtin_amdgcn_perm(q0[3], q0[2], 0x07060302u);
  H.u[2] = __builtin_amdgcn_perm(q1[1], q1[0], 0x07060302u);
  H.u[3] = __builtin_amdgcn_perm(q1[3], q1[2], 0x07060302u);
  L.u[0] = __builtin_amdgcn_perm(q0[1], q0[0], 0x05040100u);
  L.u[1] = __builtin_amdgcn_perm(q0[3], q0[2], 0x05040100u);
  L.u[2] = __builtin_amdgcn_perm(q1[1], q1[0], 0x05040100u);
  L.u[3] = __builtin_amdgcn_perm(q1[3], q1[2], 0x05040100u);
  hi = H.s;
  lo = L.s;
}
__device__ __forceinline__ void split8v(f4 a, f4 b, b16x8 &hi, b16x8 &lo) {
#pragma unroll
  for (int j = 0; j < 4; ++j) {
    short hh, ll;
    split2(a[j], hh, ll); hi[j] = hh; lo[j] = ll;
    split2(b[j], hh, ll); hi[4 + j] = hh; lo[4 + j] = ll;
  }
}

// ---- prep: H -> bf16 hi/lo split in ws; q = exp(logQ), r = exp(logR).
// ws: Hh u16[2048] @0 | Hl @4096B | q f32[64] @8192B | r f32[32] @8448B
__global__ __launch_bounds__(256) void prep_kernel(
    const float *__restrict__ Hm, const float *__restrict__ logQ,
    const float *__restrict__ logR, void *__restrict__ ws) {
  u16 *Hh = (u16 *)ws;
  u16 *Hl = (u16 *)ws + 2048;
  float *wq = (float *)((char *)ws + 8192);
  float *wr = wq + 64;
  const int tid = (int)threadIdx.x;
  f4 a = *(const f4 *)(Hm + tid * 8);
  f4 b = *(const f4 *)(Hm + tid * 8 + 4);
  b16x8 hi, lo;
  split8v(a, b, hi, lo);
  *(b16x8 *)(Hh + tid * 8) = hi;
  *(b16x8 *)(Hl + tid * 8) = lo;
  if (tid < 64) wq[tid] = expf(logQ[tid]);
  else if (tid < 96) wr[tid - 64] = expf(logR[tid - 64]);
}

__global__ __launch_bounds__(512, 8) void kalman_fused(
    const float *__restrict__ obs, const float *__restrict__ prev_state,
    const float *__restrict__ prev_cov, const float *__restrict__ coeffs,
    const float *__restrict__ Hm, const int *__restrict__ tptr,
    const void *__restrict__ ws, float *__restrict__ out) {
  __shared__ __align__(16) unsigned char pool[40960];
  u16 *sPh = (u16 *)(pool);
  u16 *sPl = (u16 *)(pool + 8192);
  u32 *sT = (u32 *)(pool);
  u32 *sPHt = (u32 *)(pool);
  u32 *sK = (u32 *)(pool + 8192);
  u16 *sFh = (u16 *)(pool + 16384);
  u16 *sFl = (u16 *)(pool + 24576);
  u32 *sCov = (u32 *)(pool + 16384);
  // EX region overlays:
  float *sChT = (float *)(pool + 32768);   // [64][12], dead after B1
  float *sDcT = (float *)(pool + 35840);   // [64][12], dead after B1
  float *ypart = (float *)(pool + 38912);  // [8][64], dead after sy
  float *sy = (float *)(pool + 32768);     // born after B1 (over chT)
  float *sresid = (float *)(pool + 33024);
  float *sq = (float *)(pool + 33152);
  float *sr = (float *)(pool + 33408);
  float *sS = (float *)(pool + 33536);     // [32][36] f32, born p5

  const u16 *wHh = (const u16 *)ws;
  const u16 *wHl = (const u16 *)ws + 2048;
  const float *wq = (const float *)((const char *)ws + 8192);
  const float *wr = wq + 64;

  const int tid = (int)threadIdx.x;
  const int b = (int)blockIdx.x;
  const int w = tid >> 6;  // wave 0..7
  const int l = tid & 63;
  const int lr = l & 15;
  const int h = l >> 4;
  const int rb = w >> 1;  // row band 0..3
  const int cp = w & 1;   // column half

  // ---- p0: stage P (bf16 hi/lo split, swizzled); cheb tables (wave 0)
  {
    const float *Pg = prev_cov + (size_t)b * 4096;
#pragma unroll
    for (int e = 0; e < 2; ++e) {
      const int idx = tid + 512 * e;
      f4 v = *(const f4 *)(Pg + 4 * idx);
      const int r = idx >> 4, c = (idx & 15) * 4;
      const int x = (r & 7) << 3;
      b16x4 h4, l4;
#pragma unroll
      for (int j = 0; j < 4; ++j) {
        short hh, ll;
        split2(v[j], hh, ll);
        h4[j] = hh; l4[j] = ll;
      }
      *(b16x4 *)(sPh + r * 64 + (c ^ x)) = h4;
      *(b16x4 *)(sPl + r * 64 + (c ^ x)) = l4;
    }
    if (tid < 64) {
      // degree(t): D = degree+1 = 9 + int(1 + sin(2*pi*t/95)), D in 9..11
      const int tval = tptr[0];
      const float ang = 6.28318530717958647f * ((float)tval / 95.0f);
      const int D = 9 + (int)(1.0f + sinf(ang));
      const float xx = prev_state[b * 64 + tid];
      const float tr_ = tanhf(xx);
      const float tv = fminf(fmaxf(tr_, -1.0f + EPSC), 1.0f - EPSC);
      const float sn = sqrtf(fmaxf(1.0f - tv * tv, 0.0f));
      const float mask = (tr_ > -1.0f + EPSC && tr_ < 1.0f - EPSC) ? 1.0f : 0.0f;
      const float dth = -(1.0f - tr_ * tr_) * mask / sn;
      float *ct = sChT + tid * 12;
      float *dt = sDcT + tid * 12;
      ct[0] = 1.f; ct[1] = tv; ct[11] = 0.f;
      dt[0] = 0.f; dt[1] = -dth * sn; dt[11] = 0.f;
      float cm2 = 1.f, cm1 = tv, sm2 = 0.f, sm1 = sn;
      const float tv2 = 2.f * tv;
#pragma unroll
      for (int d = 2; d <= 10; ++d) {
        const float cc = fmaf(tv2, cm1, -cm2);
        const float ss = fmaf(tv2, sm1, -sm2);
        ct[d] = (d < D) ? cc : 0.f;
        dt[d] = (d < D) ? (-dth * (float)d * ss) : 0.f;
        cm2 = cm1; cm1 = cc; sm2 = sm1; sm1 = ss;
      }
    }
  }
  __syncthreads(); // B0

  // ---- p1: y partials + Jacobian F (8 i's per wave); F -> split swz
  {
    const int o = tid & 63, g = w;
    float yacc = 0.f;
    float fr[8];
#pragma unroll
    for (int ii = 0; ii < 8; ++ii) {
      const int i = g * 8 + ii;
      const float *cp_ = coeffs + (size_t)(i * 64 + o) * 11;
      f4 q0 = *(const f4 *)(cp_);
      f4 q1 = *(const f4 *)(cp_ + 4);
      f4 q2 = *(const f4 *)(cp_ + 7); // q2[1..3] = cp[8..10]
      const float *ct = sChT + i * 12;
      const float *dt = sDcT + i * 12;
      f4 c0 = *(const f4 *)(ct), c1 = *(const f4 *)(ct + 4),
         c2 = *(const f4 *)(ct + 8);
      f4 e0 = *(const f4 *)(dt), e1 = *(const f4 *)(dt + 4),
         e2 = *(const f4 *)(dt + 8);
      float yac = q0[0]; // ch[0] == 1
      yac = fmaf(q0[1], c0[1], yac);
      yac = fmaf(q0[2], c0[2], yac);
      yac = fmaf(q0[3], c0[3], yac);
      yac = fmaf(q1[0], c1[0], yac);
      yac = fmaf(q1[1], c1[1], yac);
      yac = fmaf(q1[2], c1[2], yac);
      yac = fmaf(q1[3], c1[3], yac);
      yac = fmaf(q2[1], c2[0], yac);
      yac = fmaf(q2[2], c2[1], yac);
      yac = fmaf(q2[3], c2[2], yac);
      float fra = q0[1] * e0[1]; // dch[0] == 0
      fra = fmaf(q0[2], e0[2], fra);
      fra = fmaf(q0[3], e0[3], fra);
      fra = fmaf(q1[0], e1[0], fra);
      fra = fmaf(q1[1], e1[1], fra);
      fra = fmaf(q1[2], e1[2], fra);
      fra = fmaf(q1[3], e1[3], fra);
      fra = fmaf(q2[1], e2[0], fra);
      fra = fmaf(q2[2], e2[1], fra);
      fra = fmaf(q2[3], e2[2], fra);
      yacc += yac;
      fr[ii] = fra;
    }
    b16x8 fh0, fl0;
#pragma unroll
    for (int j = 0; j < 8; ++j) {
      short hh, ll;
      split2(fr[j], hh, ll); fh0[j] = hh; fl0[j] = ll;
    }
    const int x = (o & 7) << 3;
    *(b16x8 *)(sFh + o * 64 + ((g * 8) ^ x)) = fh0;
    *(b16x8 *)(sFl + o * 64 + ((g * 8) ^ x)) = fl0;
    ypart[g * 64 + o] = yacc;
  }
  __syncthreads(); // B1

  // ---- sy (wave 0, over dead table space) + sq/sr copies (waves 1-2)
  if (tid < 64) {
    float s = ypart[tid];
#pragma unroll
    for (int g = 1; g < 8; ++g) s += ypart[g * 64 + tid];
    sy[tid] = s;
  } else if (tid < 128) {
    sq[tid - 64] = wq[tid - 64];
  } else if (tid < 160) {
    sr[tid - 128] = wr[tid - 128];
  }
  __builtin_amdgcn_wave_barrier(); // order sy writes before resid reads (wave 0)
  if (tid < 32) {
    float racc = obs[b * 32 + tid];
    const float *Hr = Hm + tid * 64;
#pragma unroll
    for (int s = 0; s < 64; s += 4) {
      f4 hv = *(const f4 *)(Hr + s);
      racc -= hv[0] * sy[s] + hv[1] * sy[s + 1] + hv[2] * sy[s + 2] +
              hv[3] * sy[s + 3];
    }
    sresid[tid] = racc;
  }

  // ---- p2 (MFMA): T = F * P. Wave w: rows band rb, cols [32cp, 32cp+32).
  f32x4 accT[2] = {{0.f, 0.f, 0.f, 0.f}, {0.f, 0.f, 0.f, 0.f}};
  {
    const int m = 16 * rb + lr;
    const int xA = (m & 7) << 3;
#pragma unroll
    for (int kc = 0; kc < 2; ++kc) {
      const int k = kc * 32 + h * 8;
      b16x8 Ah = *(const b16x8 *)(sFh + m * 64 + (k ^ xA));
      b16x8 Al = *(const b16x8 *)(sFl + m * 64 + (k ^ xA));
#pragma unroll
      for (int t2 = 0; t2 < 2; ++t2) {
        const int n = (2 * cp + t2) * 16 + lr;
        const int xB = (n & 7) << 3;
        b16x8 Bh = *(const b16x8 *)(sPh + n * 64 + (k ^ xB));
        b16x8 Bl = *(const b16x8 *)(sPl + n * 64 + (k ^ xB));
        accT[t2] = MFMA(Ah, Bh, accT[t2]);
        accT[t2] = MFMA(Al, Bh, accT[t2]);
        accT[t2] = MFMA(Ah, Bl, accT[t2]);
      }
    }
  }
  __syncthreads(); // B3: P reads drained
  {
    const int r0 = 16 * rb + h * 4;
#pragma unroll
    for (int t2 = 0; t2 < 2; ++t2)
#pragma unroll
      for (int j = 0; j < 4; ++j) {
        const int rr = r0 + j, cc = (2 * cp + t2) * 16 + lr;
        sT[rr * 64 + (cc ^ ((rr & 7) << 2))] = packsplit(accT[t2][j]);
      }
  }
  __syncthreads(); // B3b: T complete

  // ---- p3 (MFMA): cov_pred = T * F^T + diag(q)
  f32x4 accC[2] = {{0.f, 0.f, 0.f, 0.f}, {0.f, 0.f, 0.f, 0.f}};
  {
    const int m = 16 * rb + lr;
    const int xA = (m & 7) << 2;
    const u32 *Tb = sT + m * 64;
#pragma unroll
    for (int kc = 0; kc < 2; ++kc) {
      const int k = kc * 32 + h * 8;
      u32x4 q0 = *(const u32x4 *)(Tb + (k ^ xA));
      u32x4 q1 = *(const u32x4 *)(Tb + ((k + 4) ^ xA));
      b16x8 Ah, Al;
      unpack8(q0, q1, Ah, Al);
#pragma unroll
      for (int t2 = 0; t2 < 2; ++t2) {
        const int n = (2 * cp + t2) * 16 + lr;
        const int xB = (n & 7) << 3;
        b16x8 Bh = *(const b16x8 *)(sFh + n * 64 + (k ^ xB));
        b16x8 Bl = *(const b16x8 *)(sFl + n * 64 + (k ^ xB));
        accC[t2] = MFMA(Ah, Bh, accC[t2]);
        accC[t2] = MFMA(Al, Bh, accC[t2]);
        accC[t2] = MFMA(Ah, Bl, accC[t2]);
      }
    }
  }
  __syncthreads(); // B4: F and T reads drained
  {
    const int r0 = 16 * rb + h * 4;
#pragma unroll
    for (int t2 = 0; t2 < 2; ++t2)
#pragma unroll
      for (int j = 0; j < 4; ++j) {
        const int rr = r0 + j, cc = (2 * cp + t2) * 16 + lr;
        float v = accC[t2][j];
        if (rr == cc) v += sq[rr];
        sCov[rr * 64 + (cc ^ ((rr & 7) << 2))] = packsplit(v);
      }
  }
  __syncthreads(); // B4b: cov complete

  // ---- p4 (MFMA): PHt = cov_pred * H^T. Wave w: rows band rb, col tile cp.
  {
    f32x4 acc = {0.f, 0.f, 0.f, 0.f};
    const int m = 16 * rb + lr;
    const int xA = (m & 7) << 2;
    const u32 *Cb = sCov + m * 64;
    const int n = cp * 16 + lr;
#pragma unroll
    for (int kc = 0; kc < 2; ++kc) {
      const int k = kc * 32 + h * 8;
      u32x4 q0 = *(const u32x4 *)(Cb + (k ^ xA));
      u32x4 q1 = *(const u32x4 *)(Cb + ((k + 4) ^ xA));
      b16x8 Ah, Al;
      unpack8(q0, q1, Ah, Al);
      b16x8 Bh = *(const b16x8 *)(wHh + n * 64 + k);
      b16x8 Bl = *(const b16x8 *)(wHl + n * 64 + k);
      acc = MFMA(Ah, Bh, acc);
      acc = MFMA(Al, Bh, acc);
      acc = MFMA(Ah, Bl, acc);
    }
    const int r0 = 16 * rb + h * 4;
#pragma unroll
    for (int j = 0; j < 4; ++j) {
      const int rr = r0 + j, cc = cp * 16 + lr;
      sPHt[rr * 32 + (cc ^ ((rr & 7) << 2))] = packsplit(acc[j]);
    }
  }
  __syncthreads(); // B5: PHt complete

  // ---- p5 (MFMA): S = H * PHt + diag(r); waves 0..3 -> tile (w>>1, w&1)
  if (w < 4) {
    f32x4 acc = {0.f, 0.f, 0.f, 0.f};
    const int m = rb * 16 + lr;
    const int n = cp * 16 + lr;
#pragma unroll
    for (int kc = 0; kc < 2; ++kc) {
      const int k = kc * 32 + h * 8;
      b16x8 Ah = *(const b16x8 *)(wHh + m * 64 + k);
      b16x8 Al = *(const b16x8 *)(wHl + m * 64 + k);
      u32x4 q0, q1;
#pragma unroll
      for (int j = 0; j < 4; ++j)
        q0[j] = sPHt[(k + j) * 32 + (n ^ (j << 2))];
#pragma unroll
      for (int j = 0; j < 4; ++j)
        q1[j] = sPHt[(k + 4 + j) * 32 + (n ^ ((4 + j) << 2))];
      b16x8 Bh, Bl;
      unpack8(q0, q1, Bh, Bl);
      acc = MFMA(Ah, Bh, acc);
      acc = MFMA(Al, Bh, acc);
      acc = MFMA(Ah, Bl, acc);
    }
    const int r0 = rb * 16 + h * 4;
#pragma unroll
    for (int j = 0; j < 4; ++j) {
      const int rr = r0 + j, cc = cp * 16 + lr;
      float v = acc[j];
      if (rr == cc) v += sr[rr];
      sS[rr * 36 + cc] = v;
    }
  }
  __syncthreads(); // B6

  // ---- p6: S^-1 in-register Gauss-Jordan on wave 0 (no pivoting, SPD>=I)
  if (w == 0) {
    const int mr = l >> 1, half = l & 1;
    float s0[16];
    const float *gbase = sS + mr * 36 + half * 16;
    {
      f4 v0 = *(const f4 *)(gbase + 0), v1 = *(const f4 *)(gbase + 4);
      f4 v2 = *(const f4 *)(gbase + 8), v3 = *(const f4 *)(gbase + 12);
#pragma unroll
      for (int j = 0; j < 4; ++j) {
        s0[j] = v0[j]; s0[4 + j] = v1[j]; s0[8 + j] = v2[j]; s0[12 + j] = v3[j];
      }
    }
#pragma unroll
    for (int p = 0; p < 32; ++p) {
      const int ph = p >> 4, pi = p & 15;
      float prow[16];
#pragma unroll
      for (int j = 0; j < 16; ++j) prow[j] = __shfl(s0[j], 2 * p + half, 64);
      const float dpp = __shfl(s0[pi], 2 * p + ph, 64);
      const float d = 1.0f / dpp;
      const float fv = __shfl(s0[pi], (l & 62) + ph, 64);
      if (mr == p) {
#pragma unroll
        for (int j = 0; j < 16; ++j) s0[j] = prow[j] * d;
        if (half == ph) s0[pi] = d;
      } else {
        const float fd = fv * d;
#pragma unroll
        for (int j = 0; j < 16; ++j) s0[j] = fmaf(-fd, prow[j], s0[j]);
        if (half == ph) s0[pi] = -fd;
      }
    }
    float *wbase = sS + mr * 36 + half * 16;
    f4 w0 = {s0[0], s0[1], s0[2], s0[3]};
    f4 w1 = {s0[4], s0[5], s0[6], s0[7]};
    f4 w2 = {s0[8], s0[9], s0[10], s0[11]};
    f4 w3 = {s0[12], s0[13], s0[14], s0[15]};
    *(f4 *)(wbase + 0) = w0;
    *(f4 *)(wbase + 4) = w1;
    *(f4 *)(wbase + 8) = w2;
    *(f4 *)(wbase + 12) = w3;
  }
  __syncthreads(); // B7

  // ---- p7 (MFMA): K = PHt * S^-1. Wave w: rows band rb, col tile cp.
  {
    f32x4 acc = {0.f, 0.f, 0.f, 0.f};
    const int m = 16 * rb + lr;
    const int xA = (m & 7) << 2;
    const int k = h * 8;
    u32x4 q0 = *(const u32x4 *)(sPHt + m * 32 + (k ^ xA));
    u32x4 q1 = *(const u32x4 *)(sPHt + m * 32 + ((k + 4) ^ xA));
    b16x8 Ah, Al;
    unpack8(q0, q1, Ah, Al);
    const int n = cp * 16 + lr;
    f4 b0 = *(const f4 *)(sS + n * 36 + k);
    f4 b1 = *(const f4 *)(sS + n * 36 + k + 4);
    b16x8 Bh, Bl;
    split8v(b0, b1, Bh, Bl);
    acc = MFMA(Ah, Bh, acc);
    acc = MFMA(Al, Bh, acc);
    acc = MFMA(Ah, Bl, acc);
    const int r0 = 16 * rb + h * 4;
#pragma unroll
    for (int j = 0; j < 4; ++j) {
      const int rr = r0 + j, cc = cp * 16 + lr;
      sK[rr * 32 + (cc ^ ((rr & 7) << 2))] = packsplit(acc[j]);
    }
  }
  __syncthreads(); // B8: K complete

  // ---- p8: state_update (wave 0) + cov_update = cov_pred - K*PHt^T
  if (tid < 64) {
    float su = sy[tid];
    const int x = (tid & 7) << 2;
    const u32 *Kb = sK + tid * 32;
#pragma unroll
    for (int c0 = 0; c0 < 32; c0 += 4) {
      u32x4 q = *(const u32x4 *)(Kb + (c0 ^ x));
#pragma unroll
      for (int j = 0; j < 4; ++j)
        su = fmaf(unpackf(q[j]), sresid[c0 + j], su);
    }
    out[b * 64 + tid] = su;
  }
  {
    const int m = 16 * rb + lr;
    const int xA = (m & 7) << 2;
    const int k = h * 8;
    u32x4 q0 = *(const u32x4 *)(sK + m * 32 + (k ^ xA));
    u32x4 q1 = *(const u32x4 *)(sK + m * 32 + ((k + 4) ^ xA));
#pragma unroll
    for (int j = 0; j < 4; ++j) { // negate both halves: -K
      q0[j] ^= 0x80008000u;
      q1[j] ^= 0x80008000u;
    }
    b16x8 Ah, Al;
    unpack8(q0, q1, Ah, Al);
    const int r0 = 16 * rb + h * 4;
    float *outc = out + CU_OFF + (size_t)b * 4096;
#pragma unroll
    for (int t2 = 0; t2 < 2; ++t2) {
      const int n = (2 * cp + t2) * 16 + lr;
      const int xB = (n & 7) << 2;
      u32x4 p0 = *(const u32x4 *)(sPHt + n * 32 + (k ^ xB));
      u32x4 p1 = *(const u32x4 *)(sPHt + n * 32 + ((k + 4) ^ xB));
      b16x8 Bh, Bl;
      unpack8(p0, p1, Bh, Bl);
      f32x4 acc;
#pragma unroll
      for (int j = 0; j < 4; ++j) {
        const int rr = r0 + j;
        acc[j] = unpackf(sCov[rr * 64 + (n ^ ((rr & 7) << 2))]);
      }
      acc = MFMA(Ah, Bh, acc);
      acc = MFMA(Al, Bh, acc);
      acc = MFMA(Ah, Bl, acc);
#pragma unroll
      for (int j = 0; j < 4; ++j) {
        const int rr = r0 + j;
        outc[rr * 64 + n] = acc[j];
        if (rr == n) out[CD_OFF + b * 64 + rr] = acc[j];
      }
    }
  }
}

extern "C" void kernel_launch(void *const *d_in, const int *in_sizes, int n_in,
                              void *d_out, int out_size, void *d_ws,
                              size_t ws_size, hipStream_t stream) {
  const float *obs = (const float *)d_in[0];
  const float *prev_state = (const float *)d_in[1];
  const float *prev_cov = (const float *)d_in[2];
  const float *coeffs = (const float *)d_in[3];
  const float *Hm = (const float *)d_in[4];
  const float *logQ = (const float *)d_in[5];
  const float *logR = (const float *)d_in[6];
  const int *tptr = (const int *)d_in[7];
  (void)in_sizes; (void)n_in; (void)out_size; (void)ws_size;
  prep_kernel<<<dim3(1), dim3(256), 0, stream>>>(Hm, logQ, logR, d_ws);
  kalman_fused<<<dim3(4096), dim3(512), 0, stream>>>(
      obs, prev_state, prev_cov, coeffs, Hm, tptr, d_ws, (float *)d_out);
}

// Round 10
// 143.217 us; speedup vs baseline: 1.1880x; 1.1880x over previous
//
#include <hip/hip_runtime.h>
#include <math.h>

// DifferentiableKalmanCell: B=4096, STATE=64, OBS=32, coeffs (64,64,11), t scalar.
// R10: TWO batches per 256-thread block (ILP instead of TLP; r9 showed 32-wave
// occupancy forces VGPR=32 -> spills). LDS 81920 = exactly 2 blocks/CU;
// VGPR budget 128 (2 waves/SIMD quantum) holds two independent dep chains.
// Per-batch layout (s in {0,1}):
//   matrix M_s = pool + s*32768: Ph|Pl(u16 swz) -> T(u32) -> PHt|K ; Fh|Fl -> cov
//   extra  E_s = pool + 65536 + s*8192 (floats):
//     p0-B1: ct[i*12] [0..768) | dt[768+i*12] [768..1536) | ypart [1536..1792)
//     post-B1: sy[0..64) resid[64..96) q[96..160) r[160..192) S[192..1344)

typedef float f4 __attribute__((ext_vector_type(4)));
typedef float f32x4 __attribute__((ext_vector_type(4)));
typedef short b16x8 __attribute__((ext_vector_type(8)));
typedef short b16x4 __attribute__((ext_vector_type(4)));
typedef unsigned int u32;
typedef unsigned int u32x4 __attribute__((ext_vector_type(4)));
typedef unsigned short u16;

#define EPSC 1e-7f
#define MFMA(a, b, c) __builtin_amdgcn_mfma_f32_16x16x32_bf16(a, b, c, 0, 0, 0)
static constexpr size_t CU_OFF = 4096 * 64;
static constexpr size_t CD_OFF = CU_OFF + 4096ull * 4096;

__device__ __forceinline__ void split2(float x, short &h, short &l) {
  u32 u = __float_as_uint(x);
  h = (short)(u >> 16);
  float rem = x - __uint_as_float(u & 0xffff0000u);
  l = (short)(__float_as_uint(rem) >> 16);
}
__device__ __forceinline__ u32 packsplit(float x) {
  u32 u = __float_as_uint(x) & 0xffff0000u;
  float rem = x - __uint_as_float(u);
  return u | (__float_as_uint(rem) >> 16);
}
__device__ __forceinline__ float unpackf(u32 v) {
  return __uint_as_float(v & 0xffff0000u) + __uint_as_float(v << 16);
}
union U8 { u32x4 u; b16x8 s; };
__device__ __forceinline__ void unpack8(u32x4 q0, u32x4 q1, b16x8 &hi,
                                        b16x8 &lo) {
  U8 H, L;
  H.u[0] = __builtin_amdgcn_perm(q0[1], q0[0], 0x07060302u);
  H.u[1] = __builtin_amdgcn_perm(q0[3], q0[2], 0x07060302u);
  H.u[2] = __builtin_amdgcn_perm(q1[1], q1[0], 0x07060302u);
  H.u[3] = __builtin_amdgcn_perm(q1[3], q1[2], 0x07060302u);
  L.u[0] = __builtin_amdgcn_perm(q0[1], q0[0], 0x05040100u);
  L.u[1] = __builtin_amdgcn_perm(q0[3], q0[2], 0x05040100u);
  L.u[2] = __builtin_amdgcn_perm(q1[1], q1[0], 0x05040100u);
  L.u[3] = __builtin_amdgcn_perm(q1[3], q1[2], 0x05040100u);
  hi = H.s;
  lo = L.s;
}
__device__ __forceinline__ void split8v(f4 a, f4 b, b16x8 &hi, b16x8 &lo) {
#pragma unroll
  for (int j = 0; j < 4; ++j) {
    short hh, ll;
    split2(a[j], hh, ll); hi[j] = hh; lo[j] = ll;
    split2(b[j], hh, ll); hi[4 + j] = hh; lo[4 + j] = ll;
  }
}

// ---- prep: H -> bf16 hi/lo split in ws; q = exp(logQ), r = exp(logR).
__global__ __launch_bounds__(256) void prep_kernel(
    const float *__restrict__ Hm, const float *__restrict__ logQ,
    const float *__restrict__ logR, void *__restrict__ ws) {
  u16 *Hh = (u16 *)ws;
  u16 *Hl = (u16 *)ws + 2048;
  float *wq = (float *)((char *)ws + 8192);
  float *wr = wq + 64;
  const int tid = (int)threadIdx.x;
  f4 a = *(const f4 *)(Hm + tid * 8);
  f4 b = *(const f4 *)(Hm + tid * 8 + 4);
  b16x8 hi, lo;
  split8v(a, b, hi, lo);
  *(b16x8 *)(Hh + tid * 8) = hi;
  *(b16x8 *)(Hl + tid * 8) = lo;
  if (tid < 64) wq[tid] = expf(logQ[tid]);
  else if (tid < 96) wr[tid - 64] = expf(logR[tid - 64]);
}

__global__ __launch_bounds__(256, 2) void kalman_fused(
    const float *__restrict__ obs, const float *__restrict__ prev_state,
    const float *__restrict__ prev_cov, const float *__restrict__ coeffs,
    const float *__restrict__ Hm, const int *__restrict__ tptr,
    const void *__restrict__ ws, float *__restrict__ out) {
  __shared__ __align__(16) unsigned char pool[81920];
  const u16 *wHh = (const u16 *)ws;
  const u16 *wHl = (const u16 *)ws + 2048;
  const float *wq = (const float *)((const char *)ws + 8192);
  const float *wr = wq + 64;

  const int tid = (int)threadIdx.x;
  const int b0 = (int)blockIdx.x * 2;
  const int w = tid >> 6;
  const int l = tid & 63;
  const int lr = l & 15;
  const int h = l >> 4;

  // ---- p0: stage P for both batches; cheb tables (waves 0-1)
#pragma unroll
  for (int s = 0; s < 2; ++s) {
    u16 *sPh = (u16 *)(pool + s * 32768);
    u16 *sPl = (u16 *)(pool + s * 32768 + 8192);
    const float *Pg = prev_cov + (size_t)(b0 + s) * 4096;
#pragma unroll
    for (int e = 0; e < 4; ++e) {
      const int idx = tid + 256 * e;
      f4 v = *(const f4 *)(Pg + 4 * idx);
      const int r = idx >> 4, c = (idx & 15) * 4;
      const int x = (r & 7) << 3;
      b16x4 h4, l4;
#pragma unroll
      for (int j = 0; j < 4; ++j) {
        short hh, ll;
        split2(v[j], hh, ll);
        h4[j] = hh; l4[j] = ll;
      }
      *(b16x4 *)(sPh + r * 64 + (c ^ x)) = h4;
      *(b16x4 *)(sPl + r * 64 + (c ^ x)) = l4;
    }
  }
  if (tid < 128) {
    const int s = tid >> 6, i = tid & 63;
    float *E = (float *)(pool + 65536 + s * 8192);
    // degree(t): D = degree+1 = 9 + int(1 + sin(2*pi*t/95)), D in 9..11
    const int tval = tptr[0];
    const float ang = 6.28318530717958647f * ((float)tval / 95.0f);
    const int D = 9 + (int)(1.0f + sinf(ang));
    const float xx = prev_state[(b0 + s) * 64 + i];
    const float tr_ = tanhf(xx);
    const float tv = fminf(fmaxf(tr_, -1.0f + EPSC), 1.0f - EPSC);
    const float sn = sqrtf(fmaxf(1.0f - tv * tv, 0.0f));
    const float mask = (tr_ > -1.0f + EPSC && tr_ < 1.0f - EPSC) ? 1.0f : 0.0f;
    const float dth = -(1.0f - tr_ * tr_) * mask / sn;
    float *ct = E + i * 12;
    float *dt = E + 768 + i * 12;
    ct[0] = 1.f; ct[1] = tv; ct[11] = 0.f;
    dt[0] = 0.f; dt[1] = -dth * sn; dt[11] = 0.f;
    float cm2 = 1.f, cm1 = tv, sm2 = 0.f, sm1 = sn;
    const float tv2 = 2.f * tv;
#pragma unroll
    for (int d = 2; d <= 10; ++d) {
      const float cc = fmaf(tv2, cm1, -cm2);
      const float ss = fmaf(tv2, sm1, -sm2);
      ct[d] = (d < D) ? cc : 0.f;
      dt[d] = (d < D) ? (-dth * (float)d * ss) : 0.f;
      cm2 = cm1; cm1 = cc; sm2 = sm1; sm1 = ss;
    }
  }
  __syncthreads(); // B0

  // ---- p1: y partials + Jacobian F per batch (table broadcast)
#pragma unroll
  for (int s = 0; s < 2; ++s) {
    const float *E = (const float *)(pool + 65536 + s * 8192);
    u16 *sFh = (u16 *)(pool + s * 32768 + 16384);
    u16 *sFl = (u16 *)(pool + s * 32768 + 24576);
    float *ypart = (float *)(pool + 65536 + s * 8192) + 1536;
    const int o = tid & 63, g = tid >> 6;
    float yacc = 0.f;
    float fr[16];
#pragma unroll
    for (int ii = 0; ii < 16; ++ii) {
      const int i = g * 16 + ii;
      const float *cp = coeffs + (size_t)(i * 64 + o) * 11;
      f4 q0 = *(const f4 *)(cp);
      f4 q1 = *(const f4 *)(cp + 4);
      f4 q2 = *(const f4 *)(cp + 7); // q2[1..3] = cp[8..10]
      const float *ct = E + i * 12;
      const float *dt = E + 768 + i * 12;
      f4 c0 = *(const f4 *)(ct), c1 = *(const f4 *)(ct + 4),
         c2 = *(const f4 *)(ct + 8);
      f4 e0 = *(const f4 *)(dt), e1 = *(const f4 *)(dt + 4),
         e2 = *(const f4 *)(dt + 8);
      float yac = q0[0]; // ct[0] == 1
      yac = fmaf(q0[1], c0[1], yac);
      yac = fmaf(q0[2], c0[2], yac);
      yac = fmaf(q0[3], c0[3], yac);
      yac = fmaf(q1[0], c1[0], yac);
      yac = fmaf(q1[1], c1[1], yac);
      yac = fmaf(q1[2], c1[2], yac);
      yac = fmaf(q1[3], c1[3], yac);
      yac = fmaf(q2[1], c2[0], yac);
      yac = fmaf(q2[2], c2[1], yac);
      yac = fmaf(q2[3], c2[2], yac);
      float fra = q0[1] * e0[1]; // dt[0] == 0
      fra = fmaf(q0[2], e0[2], fra);
      fra = fmaf(q0[3], e0[3], fra);
      fra = fmaf(q1[0], e1[0], fra);
      fra = fmaf(q1[1], e1[1], fra);
      fra = fmaf(q1[2], e1[2], fra);
      fra = fmaf(q1[3], e1[3], fra);
      fra = fmaf(q2[1], e2[0], fra);
      fra = fmaf(q2[2], e2[1], fra);
      fra = fmaf(q2[3], e2[2], fra);
      yacc += yac;
      fr[ii] = fra;
    }
    b16x8 fh0, fh1, fl0, fl1;
#pragma unroll
    for (int j = 0; j < 8; ++j) {
      short hh, ll;
      split2(fr[j], hh, ll); fh0[j] = hh; fl0[j] = ll;
      split2(fr[8 + j], hh, ll); fh1[j] = hh; fl1[j] = ll;
    }
    const int x = (o & 7) << 3;
    *(b16x8 *)(sFh + o * 64 + ((g * 16) ^ x)) = fh0;
    *(b16x8 *)(sFh + o * 64 + ((g * 16 + 8) ^ x)) = fh1;
    *(b16x8 *)(sFl + o * 64 + ((g * 16) ^ x)) = fl0;
    *(b16x8 *)(sFl + o * 64 + ((g * 16 + 8) ^ x)) = fl1;
    ypart[g * 64 + o] = yacc;
  }
  __syncthreads(); // B1

  // ---- sy (wave 0, both batches), sq/sr copies (waves 1-3), then residual
  if (tid < 64) {
#pragma unroll
    for (int s = 0; s < 2; ++s) {
      float *E = (float *)(pool + 65536 + s * 8192);
      const float *ypart = E + 1536;
      E[tid] = ypart[tid] + ypart[64 + tid] + ypart[128 + tid] +
               ypart[192 + tid]; // sy @ E[0..64)
    }
  } else if (tid < 192) {
    const int s = (tid - 64) >> 6, idx = (tid - 64) & 63;
    float *E = (float *)(pool + 65536 + s * 8192);
    E[96 + idx] = wq[idx]; // sq @ E[96..160)
  } else {
    const int s = (tid - 192) >> 5, idx = (tid - 192) & 31;
    float *E = (float *)(pool + 65536 + s * 8192);
    E[160 + idx] = wr[idx]; // sr @ E[160..192)
  }
  __builtin_amdgcn_wave_barrier(); // order sy before resid reads (wave 0)
  if (tid < 64) { // lanes 0-31: batch 0 row l; lanes 32-63: batch 1 row l-32
    const int s = l >> 5, r = l & 31;
    float *E = (float *)(pool + 65536 + s * 8192);
    float racc = obs[(b0 + s) * 32 + r];
    const float *Hr = Hm + r * 64;
#pragma unroll
    for (int c = 0; c < 64; c += 4) {
      f4 hv = *(const f4 *)(Hr + c);
      racc -= hv[0] * E[c] + hv[1] * E[c + 1] + hv[2] * E[c + 2] +
              hv[3] * E[c + 3];
    }
    E[64 + r] = racc; // sresid @ E[64..96)
  }

  // ---- p2 (MFMA): T_s = F_s * P_s (P symmetric -> B-frag = row read)
  f32x4 accT[2][4] = {};
#pragma unroll
  for (int s = 0; s < 2; ++s) {
    const u16 *sFh = (const u16 *)(pool + s * 32768 + 16384);
    const u16 *sFl = (const u16 *)(pool + s * 32768 + 24576);
    const u16 *sPh = (const u16 *)(pool + s * 32768);
    const u16 *sPl = (const u16 *)(pool + s * 32768 + 8192);
    const int m = 16 * w + lr;
    const int xA = (m & 7) << 3;
#pragma unroll
    for (int kc = 0; kc < 2; ++kc) {
      const int k = kc * 32 + h * 8;
      b16x8 Ah = *(const b16x8 *)(sFh + m * 64 + (k ^ xA));
      b16x8 Al = *(const b16x8 *)(sFl + m * 64 + (k ^ xA));
#pragma unroll
      for (int t = 0; t < 4; ++t) {
        const int n = t * 16 + lr;
        const int xB = (n & 7) << 3;
        b16x8 Bh = *(const b16x8 *)(sPh + n * 64 + (k ^ xB));
        b16x8 Bl = *(const b16x8 *)(sPl + n * 64 + (k ^ xB));
        accT[s][t] = MFMA(Ah, Bh, accT[s][t]);
        accT[s][t] = MFMA(Al, Bh, accT[s][t]);
        accT[s][t] = MFMA(Ah, Bl, accT[s][t]);
      }
    }
  }
  __syncthreads(); // B3: P reads drained; overwrite with packed T
#pragma unroll
  for (int s = 0; s < 2; ++s) {
    u32 *sT = (u32 *)(pool + s * 32768);
    const int r0 = 16 * w + h * 4;
#pragma unroll
    for (int t = 0; t < 4; ++t)
#pragma unroll
      for (int j = 0; j < 4; ++j) {
        const int rr = r0 + j, cc = t * 16 + lr;
        sT[rr * 64 + (cc ^ ((rr & 7) << 2))] = packsplit(accT[s][t][j]);
      }
  }

  // ---- p3 (MFMA): cov_s = T_s * F_s^T + diag(q). A = T band-local.
  f32x4 accC[2][4] = {};
#pragma unroll
  for (int s = 0; s < 2; ++s) {
    const u32 *sT = (const u32 *)(pool + s * 32768);
    const u16 *sFh = (const u16 *)(pool + s * 32768 + 16384);
    const u16 *sFl = (const u16 *)(pool + s * 32768 + 24576);
    const int m = 16 * w + lr;
    const int xA = (m & 7) << 2;
    const u32 *Tb = sT + m * 64;
#pragma unroll
    for (int kc = 0; kc < 2; ++kc) {
      const int k = kc * 32 + h * 8;
      u32x4 q0 = *(const u32x4 *)(Tb + (k ^ xA));
      u32x4 q1 = *(const u32x4 *)(Tb + ((k + 4) ^ xA));
      b16x8 Ah, Al;
      unpack8(q0, q1, Ah, Al);
#pragma unroll
      for (int t = 0; t < 4; ++t) {
        const int n = t * 16 + lr;
        const int xB = (n & 7) << 3;
        b16x8 Bh = *(const b16x8 *)(sFh + n * 64 + (k ^ xB));
        b16x8 Bl = *(const b16x8 *)(sFl + n * 64 + (k ^ xB));
        accC[s][t] = MFMA(Ah, Bh, accC[s][t]);
        accC[s][t] = MFMA(Al, Bh, accC[s][t]);
        accC[s][t] = MFMA(Ah, Bl, accC[s][t]);
      }
    }
  }
  __syncthreads(); // B4: F and T reads drained; overwrite F with packed cov
#pragma unroll
  for (int s = 0; s < 2; ++s) {
    u32 *sCov = (u32 *)(pool + s * 32768 + 16384);
    const float *E = (const float *)(pool + 65536 + s * 8192);
    const int r0 = 16 * w + h * 4;
#pragma unroll
    for (int t = 0; t < 4; ++t)
#pragma unroll
      for (int j = 0; j < 4; ++j) {
        const int rr = r0 + j, cc = t * 16 + lr;
        float v = accC[s][t][j];
        if (rr == cc) v += E[96 + rr]; // + q
        sCov[rr * 64 + (cc ^ ((rr & 7) << 2))] = packsplit(v);
      }
  }

  // ---- p4 (MFMA): PHt_s = cov_s * H^T (A = cov band-local; B = ws planes)
#pragma unroll
  for (int s = 0; s < 2; ++s) {
    const u32 *sCov = (const u32 *)(pool + s * 32768 + 16384);
    u32 *sPHt = (u32 *)(pool + s * 32768);
    f32x4 acc[2] = {{0.f, 0.f, 0.f, 0.f}, {0.f, 0.f, 0.f, 0.f}};
    const int m = 16 * w + lr;
    const int xA = (m & 7) << 2;
    const u32 *Cb = sCov + m * 64;
#pragma unroll
    for (int kc = 0; kc < 2; ++kc) {
      const int k = kc * 32 + h * 8;
      u32x4 q0 = *(const u32x4 *)(Cb + (k ^ xA));
      u32x4 q1 = *(const u32x4 *)(Cb + ((k + 4) ^ xA));
      b16x8 Ah, Al;
      unpack8(q0, q1, Ah, Al);
#pragma unroll
      for (int t = 0; t < 2; ++t) {
        const int n = t * 16 + lr;
        b16x8 Bh = *(const b16x8 *)(wHh + n * 64 + k);
        b16x8 Bl = *(const b16x8 *)(wHl + n * 64 + k);
        acc[t] = MFMA(Ah, Bh, acc[t]);
        acc[t] = MFMA(Al, Bh, acc[t]);
        acc[t] = MFMA(Ah, Bl, acc[t]);
      }
    }
    const int r0 = 16 * w + h * 4;
#pragma unroll
    for (int t = 0; t < 2; ++t)
#pragma unroll
      for (int j = 0; j < 4; ++j) {
        const int rr = r0 + j, cc = t * 16 + lr;
        sPHt[rr * 32 + (cc ^ ((rr & 7) << 2))] = packsplit(acc[t][j]);
      }
  }
  __syncthreads(); // B5

  // ---- p5 (MFMA): S_s = H * PHt_s + diag(r); wave w -> tile (w>>1, w&1)
#pragma unroll
  for (int s = 0; s < 2; ++s) {
    const u32 *sPHt = (const u32 *)(pool + s * 32768);
    float *E = (float *)(pool + 65536 + s * 8192);
    const int tr = w >> 1, tc = w & 1;
    f32x4 acc = {0.f, 0.f, 0.f, 0.f};
    const int m = tr * 16 + lr;
    const int n = tc * 16 + lr;
#pragma unroll
    for (int kc = 0; kc < 2; ++kc) {
      const int k = kc * 32 + h * 8;
      b16x8 Ah = *(const b16x8 *)(wHh + m * 64 + k);
      b16x8 Al = *(const b16x8 *)(wHl + m * 64 + k);
      u32x4 q0, q1;
#pragma unroll
      for (int j = 0; j < 4; ++j)
        q0[j] = sPHt[(k + j) * 32 + (n ^ (j << 2))];
#pragma unroll
      for (int j = 0; j < 4; ++j)
        q1[j] = sPHt[(k + 4 + j) * 32 + (n ^ ((4 + j) << 2))];
      b16x8 Bh, Bl;
      unpack8(q0, q1, Bh, Bl);
      acc = MFMA(Ah, Bh, acc);
      acc = MFMA(Al, Bh, acc);
      acc = MFMA(Ah, Bl, acc);
    }
    const int r0 = tr * 16 + h * 4;
#pragma unroll
    for (int j = 0; j < 4; ++j) {
      const int rr = r0 + j, cc = tc * 16 + lr;
      float v = acc[j];
      if (rr == cc) v += E[160 + rr]; // + r
      E[192 + rr * 36 + cc] = v;      // sS
    }
  }
  __syncthreads(); // B6

  // ---- p6: S^-1 Gauss-Jordan in registers; wave 0 -> batch 0, wave 1 -> 1
  if (w < 2) {
    float *sS = (float *)(pool + 65536 + w * 8192) + 192;
    const int mr = l >> 1, half = l & 1;
    float s0[16];
    const float *gbase = sS + mr * 36 + half * 16;
    {
      f4 v0 = *(const f4 *)(gbase + 0), v1 = *(const f4 *)(gbase + 4);
      f4 v2 = *(const f4 *)(gbase + 8), v3 = *(const f4 *)(gbase + 12);
#pragma unroll
      for (int j = 0; j < 4; ++j) {
        s0[j] = v0[j]; s0[4 + j] = v1[j]; s0[8 + j] = v2[j]; s0[12 + j] = v3[j];
      }
    }
#pragma unroll
    for (int p = 0; p < 32; ++p) {
      const int ph = p >> 4, pi = p & 15;
      float prow[16];
#pragma unroll
      for (int j = 0; j < 16; ++j) prow[j] = __shfl(s0[j], 2 * p + half, 64);
      const float dpp = __shfl(s0[pi], 2 * p + ph, 64);
      const float d = 1.0f / dpp;
      const float fv = __shfl(s0[pi], (l & 62) + ph, 64);
      if (mr == p) {
#pragma unroll
        for (int j = 0; j < 16; ++j) s0[j] = prow[j] * d;
        if (half == ph) s0[pi] = d;
      } else {
        const float fd = fv * d;
#pragma unroll
        for (int j = 0; j < 16; ++j) s0[j] = fmaf(-fd, prow[j], s0[j]);
        if (half == ph) s0[pi] = -fd;
      }
    }
    float *wbase = sS + mr * 36 + half * 16;
    f4 w0 = {s0[0], s0[1], s0[2], s0[3]};
    f4 w1 = {s0[4], s0[5], s0[6], s0[7]};
    f4 w2 = {s0[8], s0[9], s0[10], s0[11]};
    f4 w3 = {s0[12], s0[13], s0[14], s0[15]};
    *(f4 *)(wbase + 0) = w0;
    *(f4 *)(wbase + 4) = w1;
    *(f4 *)(wbase + 8) = w2;
    *(f4 *)(wbase + 12) = w3;
  }
  __syncthreads(); // B7

  // ---- p7 (MFMA): K_s = PHt_s * S_s^-1 (B row-read via S^-1 symmetry)
#pragma unroll
  for (int s = 0; s < 2; ++s) {
    const u32 *sPHt = (const u32 *)(pool + s * 32768);
    u32 *sK = (u32 *)(pool + s * 32768 + 8192);
    const float *sS = (const float *)(pool + 65536 + s * 8192) + 192;
    f32x4 acc[2] = {{0.f, 0.f, 0.f, 0.f}, {0.f, 0.f, 0.f, 0.f}};
    const int m = 16 * w + lr;
    const int xA = (m & 7) << 2;
    const int k = h * 8;
    u32x4 q0 = *(const u32x4 *)(sPHt + m * 32 + (k ^ xA));
    u32x4 q1 = *(const u32x4 *)(sPHt + m * 32 + ((k + 4) ^ xA));
    b16x8 Ah, Al;
    unpack8(q0, q1, Ah, Al);
#pragma unroll
    for (int t = 0; t < 2; ++t) {
      const int n = t * 16 + lr;
      f4 b0 = *(const f4 *)(sS + n * 36 + k);
      f4 b1 = *(const f4 *)(sS + n * 36 + k + 4);
      b16x8 Bh, Bl;
      split8v(b0, b1, Bh, Bl);
      acc[t] = MFMA(Ah, Bh, acc[t]);
      acc[t] = MFMA(Al, Bh, acc[t]);
      acc[t] = MFMA(Ah, Bl, acc[t]);
    }
    const int r0 = 16 * w + h * 4;
#pragma unroll
    for (int t = 0; t < 2; ++t)
#pragma unroll
      for (int j = 0; j < 4; ++j) {
        const int rr = r0 + j, cc = t * 16 + lr;
        sK[rr * 32 + (cc ^ ((rr & 7) << 2))] = packsplit(acc[t][j]);
      }
  }
  __syncthreads(); // B8

  // ---- p8: state_update (waves 0-1) + cov_update = cov - K*PHt^T
  if (tid < 128) {
    const int s = tid >> 6;
    const u32 *sK = (const u32 *)(pool + s * 32768 + 8192);
    const float *E = (const float *)(pool + 65536 + s * 8192);
    float su = E[l]; // sy
    const int x = (l & 7) << 2;
    const u32 *Kb = sK + l * 32;
#pragma unroll
    for (int c0 = 0; c0 < 32; c0 += 4) {
      u32x4 q = *(const u32x4 *)(Kb + (c0 ^ x));
#pragma unroll
      for (int j = 0; j < 4; ++j)
        su = fmaf(unpackf(q[j]), E[64 + c0 + j], su);
    }
    out[(b0 + s) * 64 + l] = su;
  }
#pragma unroll
  for (int s = 0; s < 2; ++s) {
    const u32 *sPHt = (const u32 *)(pool + s * 32768);
    const u32 *sK = (const u32 *)(pool + s * 32768 + 8192);
    const u32 *sCov = (const u32 *)(pool + s * 32768 + 16384);
    const int m = 16 * w + lr;
    const int xA = (m & 7) << 2;
    const int k = h * 8;
    u32x4 q0 = *(const u32x4 *)(sK + m * 32 + (k ^ xA));
    u32x4 q1 = *(const u32x4 *)(sK + m * 32 + ((k + 4) ^ xA));
#pragma unroll
    for (int j = 0; j < 4; ++j) { // negate both halves: -K
      q0[j] ^= 0x80008000u;
      q1[j] ^= 0x80008000u;
    }
    b16x8 Ah, Al;
    unpack8(q0, q1, Ah, Al);
    const int r0 = 16 * w + h * 4;
    float *outc = out + CU_OFF + (size_t)(b0 + s) * 4096;
#pragma unroll
    for (int t = 0; t < 4; ++t) {
      const int n = t * 16 + lr;
      const int xB = (n & 7) << 2;
      u32x4 p0 = *(const u32x4 *)(sPHt + n * 32 + (k ^ xB));
      u32x4 p1 = *(const u32x4 *)(sPHt + n * 32 + ((k + 4) ^ xB));
      b16x8 Bh, Bl;
      unpack8(p0, p1, Bh, Bl);
      f32x4 acc;
#pragma unroll
      for (int j = 0; j < 4; ++j) {
        const int rr = r0 + j;
        acc[j] = unpackf(sCov[rr * 64 + (n ^ ((rr & 7) << 2))]);
      }
      acc = MFMA(Ah, Bh, acc);
      acc = MFMA(Al, Bh, acc);
      acc = MFMA(Ah, Bl, acc);
#pragma unroll
      for (int j = 0; j < 4; ++j) {
        const int rr = r0 + j;
        outc[rr * 64 + n] = acc[j];
        if (rr == n) out[CD_OFF + (b0 + s) * 64 + rr] = acc[j];
      }
    }
  }
}

extern "C" void kernel_launch(void *const *d_in, const int *in_sizes, int n_in,
                              void *d_out, int out_size, void *d_ws,
                              size_t ws_size, hipStream_t stream) {
  const float *obs = (const float *)d_in[0];
  const float *prev_state = (const float *)d_in[1];
  const float *prev_cov = (const float *)d_in[2];
  const float *coeffs = (const float *)d_in[3];
  const float *Hm = (const float *)d_in[4];
  const float *logQ = (const float *)d_in[5];
  const float *logR = (const float *)d_in[6];
  const int *tptr = (const int *)d_in[7];
  (void)in_sizes; (void)n_in; (void)out_size; (void)ws_size;
  prep_kernel<<<dim3(1), dim3(256), 0, stream>>>(Hm, logQ, logR, d_ws);
  kalman_fused<<<dim3(2048), dim3(256), 0, stream>>>(
      obs, prev_state, prev_cov, coeffs, Hm, tptr, d_ws, (float *)d_out);
}